// Round 1
// baseline (945.320 us; speedup 1.0000x reference)
//
#include <hip/hip_runtime.h>

// BondAwareEGNN fused layer — MI355X bf16-MFMA implementation, round 1.
//
// Structure:
//   pack_w   x5 : fp32 weights -> bf16 "fragment-linear" layout in ws (one
//                 coalesced 16B/lane load per MFMA B-fragment, L2-hot).
//   bond_counts : per-atom endpoint counts (atomics, ws).
//   msg_kernel  : per 64 bond-batch rows: stage [h_src|h_dst] bf16 in LDS,
//                 L1 GEMM (K=256, + rank-1 dist term), silu, L2 GEMM (K=128),
//                 silu -> messages; atomic scatter into aggregated (d_out h
//                 region); coord GEMM (K=128) + dot(Wc2) + shfl reduce ->
//                 coord_weights; atomic scatter upd into d_out x region.
//   node_kernel : per 64 atom-batch rows: stage [h|aggregated], 2-layer MLP,
//                 h_out = h + delta written IN PLACE over aggregated;
//                 x_out = x + coord_update/counts fused in.
//
// MFMA fragment mappings (guide §3, m89/m91/m120 verified):
//   A: row = lane&15,  k = (lane>>4)*8 + j
//   B: col = lane&15,  k = (lane>>4)*8 + j
//   D: col = lane&15,  row = (lane>>4)*4 + reg

#define H      128
#define NA     20000
#define NB     60000
#define NBATCH 8

#define APAD 264   // 256 + 8 bf16 pad -> row stride 528B, 2-way-max bank alias
#define TPAD 136   // 128 + 8

typedef __bf16 bf16;
typedef __bf16 bf16x4 __attribute__((ext_vector_type(4)));
typedef __bf16 bf16x8 __attribute__((ext_vector_type(8)));
typedef float  f32x4  __attribute__((ext_vector_type(4)));

__device__ __forceinline__ float silu_f(float v) {
  return v / (1.0f + __expf(-v));
}

// Pack a K x 128 fp32 row-major weight matrix into bf16 fragment-linear
// layout: frag index = ((ntile*(K/32) + kstep)*64 + lane), 8 bf16 per frag.
__global__ void pack_w(const float* __restrict__ src, bf16* __restrict__ dst,
                       int K) {
  int i = blockIdx.x * 256 + threadIdx.x;
  if (i >= K * 128) return;
  int k = i >> 7, n = i & 127;
  int nt = n >> 4, ks = k >> 5;
  int lane = (((k >> 3) & 3) << 4) | (n & 15);
  int j = k & 7;
  int KS = K >> 5;
  dst[((((nt * KS + ks) * 64) + lane) << 3) + j] = (bf16)src[i];
}

__global__ void bond_counts(const int* __restrict__ bonds,
                            float* __restrict__ counts) {
  int e = blockIdx.x * 256 + threadIdx.x;
  if (e >= NB) return;
  atomicAdd(&counts[bonds[2 * e]], 1.0f);
  atomicAdd(&counts[bonds[2 * e + 1]], 1.0f);
}

__global__ __launch_bounds__(256, 2) void msg_kernel(
    const float* __restrict__ h, const float* __restrict__ x,
    const int* __restrict__ bonds,
    const bf16* __restrict__ W1p, const float* __restrict__ bm1,
    const bf16* __restrict__ W2p, const float* __restrict__ bm2,
    const float* __restrict__ w1c,   // Wm1 row 256 (dist row), fp32[128]
    const bf16* __restrict__ Wc1p, const float* __restrict__ bc1,
    const float* __restrict__ Wc2,
    float* __restrict__ agg, float* __restrict__ coordUpd) {
  __shared__ __align__(16) bf16 Albuf[64 * APAD];
  __shared__ __align__(16) bf16 Tbuf[64 * TPAD];
  __shared__ float cds[64 * 3];
  __shared__ float dists[64];
  __shared__ float bm1s[128], bm2s[128], w1cs[128], bc1s[128], wc2s[128];

  const int tid = threadIdx.x, blk = blockIdx.x;
  const int g = tid >> 6, l = tid & 63;

  // ---- stage A = [h_src | h_dst] (bf16), coord diffs, biases ----
  for (int r = g; r < 64; r += 4) {
    int Rg = blk * 64 + r;
    int bond = Rg >> 3, batch = Rg & 7;
    int s = bonds[2 * bond], dn = bonds[2 * bond + 1];
    int col4 = l * 4;
    const float* p = (col4 < H)
        ? (h + (size_t)(batch * NA + s) * H + col4)
        : (h + (size_t)(batch * NA + dn) * H + (col4 - H));
    float4 v = *(const float4*)p;
    bf16x4 t = {(bf16)v.x, (bf16)v.y, (bf16)v.z, (bf16)v.w};
    *(bf16x4*)&Albuf[r * APAD + col4] = t;
  }
  if (tid < 64) {
    int Rg = blk * 64 + tid;
    int bond = Rg >> 3, batch = Rg & 7;
    int s = bonds[2 * bond], dn = bonds[2 * bond + 1];
    const float* xs = x + (size_t)(batch * NA + s) * 3;
    const float* xd = x + (size_t)(batch * NA + dn) * 3;
    float c0 = xd[0] - xs[0], c1 = xd[1] - xs[1], c2 = xd[2] - xs[2];
    cds[tid * 3 + 0] = c0; cds[tid * 3 + 1] = c1; cds[tid * 3 + 2] = c2;
    dists[tid] = sqrtf(c0 * c0 + c1 * c1 + c2 * c2);
  }
  if (tid < 128) {
    bm1s[tid] = bm1[tid]; bm2s[tid] = bm2[tid]; w1cs[tid] = w1c[tid];
    bc1s[tid] = bc1[tid]; wc2s[tid] = Wc2[tid];
  }
  __syncthreads();

  const int lane = tid & 63;
  const int quad = lane >> 4, l16 = lane & 15;
  const int rowBase = (tid >> 6) * 16;
  const bf16x8* W1v = (const bf16x8*)W1p;
  const bf16x8* W2v = (const bf16x8*)W2p;
  const bf16x8* Wc1v = (const bf16x8*)Wc1p;

  f32x4 acc[8];
#pragma unroll
  for (int nt = 0; nt < 8; nt++) acc[nt] = (f32x4){0.f, 0.f, 0.f, 0.f};

  // ---- layer 1: K = 256 ----
  for (int ks = 0; ks < 8; ks++) {
    bf16x8 a = *(const bf16x8*)&Albuf[(rowBase + l16) * APAD + ks * 32 + quad * 8];
#pragma unroll
    for (int nt = 0; nt < 8; nt++) {
      bf16x8 b = W1v[(nt * 8 + ks) * 64 + lane];
      acc[nt] = __builtin_amdgcn_mfma_f32_16x16x32_bf16(a, b, acc[nt], 0, 0, 0);
    }
  }
#pragma unroll
  for (int nt = 0; nt < 8; nt++) {
    int col = nt * 16 + l16;
    float bb = bm1s[col], wc = w1cs[col];
#pragma unroll
    for (int reg = 0; reg < 4; reg++) {
      int row = rowBase + quad * 4 + reg;
      float v = acc[nt][reg] + bb + dists[row] * wc;
      Tbuf[row * TPAD + col] = (bf16)silu_f(v);   // same-wave rows: no barrier
    }
  }

  // ---- layer 2: K = 128 -> messages ----
#pragma unroll
  for (int nt = 0; nt < 8; nt++) acc[nt] = (f32x4){0.f, 0.f, 0.f, 0.f};
  for (int ks = 0; ks < 4; ks++) {
    bf16x8 a = *(const bf16x8*)&Tbuf[(rowBase + l16) * TPAD + ks * 32 + quad * 8];
#pragma unroll
    for (int nt = 0; nt < 8; nt++) {
      bf16x8 b = W2v[(nt * 4 + ks) * 64 + lane];
      acc[nt] = __builtin_amdgcn_mfma_f32_16x16x32_bf16(a, b, acc[nt], 0, 0, 0);
    }
  }

  int srcR[4], dstR[4], batR[4];
#pragma unroll
  for (int reg = 0; reg < 4; reg++) {
    int row = rowBase + quad * 4 + reg;
    int Rg = blk * 64 + row;
    int bond = Rg >> 3;
    batR[reg] = Rg & 7;
    srcR[reg] = bonds[2 * bond];
    dstR[reg] = bonds[2 * bond + 1];
  }

  // messages: scatter-add into aggregated + stash bf16 copy for coord GEMM.
  // Msg reuses Albuf with the SAME stride (APAD) so each wave only touches
  // its own 16 rows (no cross-wave hazard with layer-1 A reads).
  bf16* Msg = Albuf;
#pragma unroll
  for (int nt = 0; nt < 8; nt++) {
    int col = nt * 16 + l16;
    float bb = bm2s[col];
#pragma unroll
    for (int reg = 0; reg < 4; reg++) {
      int row = rowBase + quad * 4 + reg;
      float m = silu_f(acc[nt][reg] + bb);
      Msg[row * APAD + col] = (bf16)m;
      atomicAdd(&agg[(size_t)(batR[reg] * NA + dstR[reg]) * H + col], m);
      atomicAdd(&agg[(size_t)(batR[reg] * NA + srcR[reg]) * H + col], m);
    }
  }

  // ---- coord head: silu(messages @ Wc1 + bc1) @ Wc2 ----
#pragma unroll
  for (int nt = 0; nt < 8; nt++) acc[nt] = (f32x4){0.f, 0.f, 0.f, 0.f};
  for (int ks = 0; ks < 4; ks++) {
    bf16x8 a = *(const bf16x8*)&Msg[(rowBase + l16) * APAD + ks * 32 + quad * 8];
#pragma unroll
    for (int nt = 0; nt < 8; nt++) {
      bf16x8 b = Wc1v[(nt * 4 + ks) * 64 + lane];
      acc[nt] = __builtin_amdgcn_mfma_f32_16x16x32_bf16(a, b, acc[nt], 0, 0, 0);
    }
  }
  float cwp[4] = {0.f, 0.f, 0.f, 0.f};
#pragma unroll
  for (int nt = 0; nt < 8; nt++) {
    int col = nt * 16 + l16;
    float bb = bc1s[col], w2 = wc2s[col];
#pragma unroll
    for (int reg = 0; reg < 4; reg++)
      cwp[reg] += silu_f(acc[nt][reg] + bb) * w2;
  }
#pragma unroll
  for (int reg = 0; reg < 4; reg++) {
    float s = cwp[reg];
    s += __shfl_xor(s, 1);
    s += __shfl_xor(s, 2);
    s += __shfl_xor(s, 4);
    s += __shfl_xor(s, 8);
    cwp[reg] = s;
  }
  if (l16 == 0) {
#pragma unroll
    for (int reg = 0; reg < 4; reg++) {
      int row = rowBase + quad * 4 + reg;
      float inv = 1.0f / (dists[row] + 1e-8f);
      float cw = cwp[reg];
#pragma unroll
      for (int c = 0; c < 3; c++) {
        float u = cds[row * 3 + c] * inv * cw;
        atomicAdd(&coordUpd[(size_t)(batR[reg] * NA + dstR[reg]) * 3 + c],  u);
        atomicAdd(&coordUpd[(size_t)(batR[reg] * NA + srcR[reg]) * 3 + c], -u);
      }
    }
  }
}

__global__ __launch_bounds__(256, 2) void node_kernel(
    const float* __restrict__ h, const float* __restrict__ x,
    const bf16* __restrict__ Wn1p, const float* __restrict__ bn1,
    const bf16* __restrict__ Wn2p, const float* __restrict__ bn2,
    const float* __restrict__ counts,
    float* __restrict__ hout,    // d_out h region (holds aggregated on entry)
    float* __restrict__ xout) {  // d_out x region (holds coord_update on entry)
  __shared__ __align__(16) bf16 Albuf[64 * APAD];
  __shared__ __align__(16) bf16 Tbuf[64 * TPAD];
  __shared__ float bn1s[128], bn2s[128];

  const int tid = threadIdx.x, blk = blockIdx.x;
  const int g = tid >> 6, l = tid & 63;

  for (int r = g; r < 64; r += 4) {
    size_t Rg = (size_t)blk * 64 + r;   // == batch*NA + atom
    int col4 = l * 4;
    const float* p = (col4 < H) ? (h + Rg * H + col4)
                                : (hout + Rg * H + (col4 - H));
    float4 v = *(const float4*)p;
    bf16x4 t = {(bf16)v.x, (bf16)v.y, (bf16)v.z, (bf16)v.w};
    *(bf16x4*)&Albuf[r * APAD + col4] = t;
  }
  if (tid < 128) { bn1s[tid] = bn1[tid]; bn2s[tid] = bn2[tid]; }
  if (tid < 192) {  // fused x_out finalize: x + coord_update / counts
    int r = tid / 3, c = tid % 3;
    size_t Rg = (size_t)blk * 64 + r;
    int a = (int)(Rg % NA);
    float cnt = counts[a];
    cnt = cnt < 1.0f ? 1.0f : cnt;
    xout[Rg * 3 + c] = x[Rg * 3 + c] + xout[Rg * 3 + c] / cnt;
  }
  __syncthreads();

  const int lane = tid & 63;
  const int quad = lane >> 4, l16 = lane & 15;
  const int rowBase = (tid >> 6) * 16;
  const bf16x8* W1v = (const bf16x8*)Wn1p;
  const bf16x8* W2v = (const bf16x8*)Wn2p;

  f32x4 acc[8];
#pragma unroll
  for (int nt = 0; nt < 8; nt++) acc[nt] = (f32x4){0.f, 0.f, 0.f, 0.f};

  for (int ks = 0; ks < 8; ks++) {
    bf16x8 a = *(const bf16x8*)&Albuf[(rowBase + l16) * APAD + ks * 32 + quad * 8];
#pragma unroll
    for (int nt = 0; nt < 8; nt++) {
      bf16x8 b = W1v[(nt * 8 + ks) * 64 + lane];
      acc[nt] = __builtin_amdgcn_mfma_f32_16x16x32_bf16(a, b, acc[nt], 0, 0, 0);
    }
  }
#pragma unroll
  for (int nt = 0; nt < 8; nt++) {
    int col = nt * 16 + l16;
    float bb = bn1s[col];
#pragma unroll
    for (int reg = 0; reg < 4; reg++) {
      int row = rowBase + quad * 4 + reg;
      Tbuf[row * TPAD + col] = (bf16)silu_f(acc[nt][reg] + bb);
    }
  }

#pragma unroll
  for (int nt = 0; nt < 8; nt++) acc[nt] = (f32x4){0.f, 0.f, 0.f, 0.f};
  for (int ks = 0; ks < 4; ks++) {
    bf16x8 a = *(const bf16x8*)&Tbuf[(rowBase + l16) * TPAD + ks * 32 + quad * 8];
#pragma unroll
    for (int nt = 0; nt < 8; nt++) {
      bf16x8 b = W2v[(nt * 4 + ks) * 64 + lane];
      acc[nt] = __builtin_amdgcn_mfma_f32_16x16x32_bf16(a, b, acc[nt], 0, 0, 0);
    }
  }
#pragma unroll
  for (int nt = 0; nt < 8; nt++) {
    int col = nt * 16 + l16;
    float bb = bn2s[col];
#pragma unroll
    for (int reg = 0; reg < 4; reg++) {
      size_t Rg = (size_t)blk * 64 + rowBase + quad * 4 + reg;
      hout[Rg * H + col] = h[Rg * H + col] + acc[nt][reg] + bb;  // in-place over agg
    }
  }
}

extern "C" void kernel_launch(void* const* d_in, const int* in_sizes, int n_in,
                              void* d_out, int out_size, void* d_ws,
                              size_t ws_size, hipStream_t stream) {
  const float* h    = (const float*)d_in[0];
  const float* x    = (const float*)d_in[1];
  const int*  bonds = (const int*)d_in[2];
  const float* Wm1  = (const float*)d_in[3];
  const float* bm1  = (const float*)d_in[4];
  const float* Wm2  = (const float*)d_in[5];
  const float* bm2  = (const float*)d_in[6];
  const float* Wn1  = (const float*)d_in[7];
  const float* bn1  = (const float*)d_in[8];
  const float* Wn2  = (const float*)d_in[9];
  const float* bn2  = (const float*)d_in[10];
  const float* Wc1  = (const float*)d_in[11];
  const float* bc1  = (const float*)d_in[12];
  const float* Wc2  = (const float*)d_in[13];

  float* out = (float*)d_out;
  float* agg = out;                               // h region: agg then h_out
  float* coordUpd = out + (size_t)NBATCH * NA * H;  // x region: upd then x_out

  char* ws = (char*)d_ws;
  float* counts = (float*)ws;                 // 20000 f32
  bf16* W1p  = (bf16*)(ws + 81920);           // 32768 bf16
  bf16* W2p  = (bf16*)(ws + 147456);          // 16384
  bf16* Wn1p = (bf16*)(ws + 180224);          // 32768
  bf16* Wn2p = (bf16*)(ws + 245760);          // 16384
  bf16* Wc1p = (bf16*)(ws + 278528);          // 16384  (end: 311296 B)

  hipMemsetAsync(d_out, 0, (size_t)out_size * sizeof(float), stream);
  hipMemsetAsync(counts, 0, NA * sizeof(float), stream);

  pack_w<<<128, 256, 0, stream>>>(Wm1, W1p, 256);
  pack_w<<<64, 256, 0, stream>>>(Wm2, W2p, 128);
  pack_w<<<128, 256, 0, stream>>>(Wn1, Wn1p, 256);
  pack_w<<<64, 256, 0, stream>>>(Wn2, Wn2p, 128);
  pack_w<<<64, 256, 0, stream>>>(Wc1, Wc1p, 128);
  bond_counts<<<(NB + 255) / 256, 256, 0, stream>>>(bonds, counts);

  msg_kernel<<<NB * NBATCH / 64, 256, 0, stream>>>(
      h, x, bonds, W1p, bm1, W2p, bm2, Wm1 + 256 * H, Wc1p, bc1, Wc2,
      agg, coordUpd);
  node_kernel<<<NBATCH * NA / 64, 256, 0, stream>>>(
      h, x, Wn1p, bn1, Wn2p, bn2, counts, agg, coordUpd);
}

// Round 2
// 791.560 us; speedup vs baseline: 1.1942x; 1.1942x over previous
//
#include <hip/hip_runtime.h>

// BondAwareEGNN fused layer — round 2: kill the scatter atomics.
//
// Round-1 post-mortem: msg_kernel = 733us, MfmaUtil 3.5%, WRITE_SIZE 570MB.
// 122.9M fp32 atomicAdds into an 82MB agg buffer -> HBM RMW floor.
//
// New structure (when ws_size is big enough, ~166MB):
//   count_deg / scan_offsets / build_adj : CSR adjacency per atom (device).
//   msg_kernel<1> : GEMMs as before; messages -> ws (bf16, coalesced 16B),
//                   per-bond coord upd vector -> ws (fp32). NO atomics.
//   gather_kernel : one block per atom: agg[b,a,:] = sum msgs (fp32 acc,
//                   bf16 store to ws); x_out = x + signed-sum(upd)/deg.
//   node_kernel<1>: h_in = [h fp32 | agg bf16(ws)] -> 2-layer MLP -> h_out.
// Fallback <0> = round-1 atomic path if ws too small.

#define H      128
#define NA     20000
#define NB     60000
#define NBATCH 8

#define APAD 264   // 256 + 8 bf16 pad
#define TPAD 136   // 128 + 8

typedef __bf16 bf16;
typedef __bf16 bf16x4 __attribute__((ext_vector_type(4)));
typedef __bf16 bf16x8 __attribute__((ext_vector_type(8)));
typedef float  f32x4  __attribute__((ext_vector_type(4)));

__device__ __forceinline__ float silu_f(float v) {
  return v / (1.0f + __expf(-v));
}

// fp32 KxN(128) row-major -> bf16 fragment-linear (8 bf16 per lane-frag).
__global__ void pack_w(const float* __restrict__ src, bf16* __restrict__ dst,
                       int K) {
  int i = blockIdx.x * 256 + threadIdx.x;
  if (i >= K * 128) return;
  int k = i >> 7, n = i & 127;
  int nt = n >> 4, ks = k >> 5;
  int lane = (((k >> 3) & 3) << 4) | (n & 15);
  int j = k & 7;
  int KS = K >> 5;
  dst[((((nt * KS + ks) * 64) + lane) << 3) + j] = (bf16)src[i];
}

// ---------------- CSR build ----------------
__global__ void count_deg(const int* __restrict__ bonds,
                          int* __restrict__ degI) {
  int e = blockIdx.x * 256 + threadIdx.x;
  if (e >= NB) return;
  atomicAdd(&degI[bonds[2 * e]], 1);
  atomicAdd(&degI[bonds[2 * e + 1]], 1);
}

__global__ void scan_offsets(const int* __restrict__ deg,
                             int* __restrict__ offsets) {
  __shared__ int sh[1024];
  __shared__ int carry;
  int tid = threadIdx.x;
  if (tid == 0) carry = 0;
  __syncthreads();
  for (int base = 0; base < NA; base += 1024) {
    int i = base + tid;
    int v = (i < NA) ? deg[i] : 0;
    sh[tid] = v;
    __syncthreads();
    for (int ofs = 1; ofs < 1024; ofs <<= 1) {
      int t = (tid >= ofs) ? sh[tid - ofs] : 0;
      __syncthreads();
      sh[tid] += t;
      __syncthreads();
    }
    int incl = sh[tid];
    int c = carry;
    if (i < NA) offsets[i] = incl - v + c;  // exclusive
    __syncthreads();
    if (tid == 1023) carry = c + sh[1023];
    __syncthreads();
  }
}

__global__ void build_adj(const int* __restrict__ bonds,
                          const int* __restrict__ offsets,
                          int* __restrict__ cursor, int* __restrict__ adj) {
  int e = blockIdx.x * 256 + threadIdx.x;
  if (e >= NB) return;
  int s = bonds[2 * e], d = bonds[2 * e + 1];
  int p = atomicAdd(&cursor[s], 1);
  adj[offsets[s] + p] = (e << 1);        // flag 0: src endpoint (coord sign -)
  p = atomicAdd(&cursor[d], 1);
  adj[offsets[d] + p] = (e << 1) | 1;    // flag 1: dst endpoint (coord sign +)
}

// legacy fallback helper
__global__ void bond_counts(const int* __restrict__ bonds,
                            float* __restrict__ counts) {
  int e = blockIdx.x * 256 + threadIdx.x;
  if (e >= NB) return;
  atomicAdd(&counts[bonds[2 * e]], 1.0f);
  atomicAdd(&counts[bonds[2 * e + 1]], 1.0f);
}

// ---------------- message kernel ----------------
// MODE 0: atomic scatter into agg(fp32, d_out) + coordUpd atomics (round-1).
// MODE 1: messages -> msgOut (bf16 ws), upd vec -> updv (fp32 ws). No atomics.
template <int MODE>
__global__ __launch_bounds__(256, 2) void msg_kernel(
    const float* __restrict__ h, const float* __restrict__ x,
    const int* __restrict__ bonds,
    const bf16* __restrict__ W1p, const float* __restrict__ bm1,
    const bf16* __restrict__ W2p, const float* __restrict__ bm2,
    const float* __restrict__ w1c,   // Wm1 row 256 (dist row), fp32[128]
    const bf16* __restrict__ Wc1p, const float* __restrict__ bc1,
    const float* __restrict__ Wc2,
    float* __restrict__ agg, float* __restrict__ coordUpd,
    bf16* __restrict__ msgOut, float* __restrict__ updv) {
  __shared__ __align__(16) bf16 Albuf[64 * APAD];
  __shared__ __align__(16) bf16 Tbuf[64 * TPAD];
  __shared__ float cds[64 * 3];
  __shared__ float dists[64];
  __shared__ float bm1s[128], bm2s[128], w1cs[128], bc1s[128], wc2s[128];

  const int tid = threadIdx.x, blk = blockIdx.x;
  const int g = tid >> 6, l = tid & 63;

  for (int r = g; r < 64; r += 4) {
    int Rg = blk * 64 + r;
    int bond = Rg >> 3, batch = Rg & 7;
    int s = bonds[2 * bond], dn = bonds[2 * bond + 1];
    int col4 = l * 4;
    const float* p = (col4 < H)
        ? (h + (size_t)(batch * NA + s) * H + col4)
        : (h + (size_t)(batch * NA + dn) * H + (col4 - H));
    float4 v = *(const float4*)p;
    bf16x4 t = {(bf16)v.x, (bf16)v.y, (bf16)v.z, (bf16)v.w};
    *(bf16x4*)&Albuf[r * APAD + col4] = t;
  }
  if (tid < 64) {
    int Rg = blk * 64 + tid;
    int bond = Rg >> 3, batch = Rg & 7;
    int s = bonds[2 * bond], dn = bonds[2 * bond + 1];
    const float* xs = x + (size_t)(batch * NA + s) * 3;
    const float* xd = x + (size_t)(batch * NA + dn) * 3;
    float c0 = xd[0] - xs[0], c1 = xd[1] - xs[1], c2 = xd[2] - xs[2];
    cds[tid * 3 + 0] = c0; cds[tid * 3 + 1] = c1; cds[tid * 3 + 2] = c2;
    dists[tid] = sqrtf(c0 * c0 + c1 * c1 + c2 * c2);
  }
  if (tid < 128) {
    bm1s[tid] = bm1[tid]; bm2s[tid] = bm2[tid]; w1cs[tid] = w1c[tid];
    bc1s[tid] = bc1[tid]; wc2s[tid] = Wc2[tid];
  }
  __syncthreads();

  const int lane = tid & 63;
  const int quad = lane >> 4, l16 = lane & 15;
  const int rowBase = (tid >> 6) * 16;
  const bf16x8* W1v = (const bf16x8*)W1p;
  const bf16x8* W2v = (const bf16x8*)W2p;
  const bf16x8* Wc1v = (const bf16x8*)Wc1p;

  f32x4 acc[8];
#pragma unroll
  for (int nt = 0; nt < 8; nt++) acc[nt] = (f32x4){0.f, 0.f, 0.f, 0.f};

  // ---- layer 1: K = 256 (+ rank-1 dist term) ----
  for (int ks = 0; ks < 8; ks++) {
    bf16x8 a = *(const bf16x8*)&Albuf[(rowBase + l16) * APAD + ks * 32 + quad * 8];
#pragma unroll
    for (int nt = 0; nt < 8; nt++) {
      bf16x8 b = W1v[(nt * 8 + ks) * 64 + lane];
      acc[nt] = __builtin_amdgcn_mfma_f32_16x16x32_bf16(a, b, acc[nt], 0, 0, 0);
    }
  }
#pragma unroll
  for (int nt = 0; nt < 8; nt++) {
    int col = nt * 16 + l16;
    float bb = bm1s[col], wc = w1cs[col];
#pragma unroll
    for (int reg = 0; reg < 4; reg++) {
      int row = rowBase + quad * 4 + reg;
      float v = acc[nt][reg] + bb + dists[row] * wc;
      Tbuf[row * TPAD + col] = (bf16)silu_f(v);   // same-wave rows
    }
  }

  // ---- layer 2: K = 128 -> messages ----
#pragma unroll
  for (int nt = 0; nt < 8; nt++) acc[nt] = (f32x4){0.f, 0.f, 0.f, 0.f};
  for (int ks = 0; ks < 4; ks++) {
    bf16x8 a = *(const bf16x8*)&Tbuf[(rowBase + l16) * TPAD + ks * 32 + quad * 8];
#pragma unroll
    for (int nt = 0; nt < 8; nt++) {
      bf16x8 b = W2v[(nt * 4 + ks) * 64 + lane];
      acc[nt] = __builtin_amdgcn_mfma_f32_16x16x32_bf16(a, b, acc[nt], 0, 0, 0);
    }
  }

  int srcR[4], dstR[4], batR[4];
  if constexpr (MODE == 0) {
#pragma unroll
    for (int reg = 0; reg < 4; reg++) {
      int row = rowBase + quad * 4 + reg;
      int Rg = blk * 64 + row;
      int bond = Rg >> 3;
      batR[reg] = Rg & 7;
      srcR[reg] = bonds[2 * bond];
      dstR[reg] = bonds[2 * bond + 1];
    }
  }

  bf16* Msg = Albuf;  // reuse, same stride: each wave touches only its 16 rows
#pragma unroll
  for (int nt = 0; nt < 8; nt++) {
    int col = nt * 16 + l16;
    float bb = bm2s[col];
#pragma unroll
    for (int reg = 0; reg < 4; reg++) {
      int row = rowBase + quad * 4 + reg;
      float m = silu_f(acc[nt][reg] + bb);
      Msg[row * APAD + col] = (bf16)m;
      if constexpr (MODE == 0) {
        atomicAdd(&agg[(size_t)(batR[reg] * NA + dstR[reg]) * H + col], m);
        atomicAdd(&agg[(size_t)(batR[reg] * NA + srcR[reg]) * H + col], m);
      }
    }
  }

  if constexpr (MODE == 1) {
    // coalesced bf16 message store: 64 rows x 128 cols, 16B per thread-iter
    __syncthreads();
    for (int i = tid; i < 64 * 16; i += 256) {
      int row = i >> 4, cg = i & 15;
      bf16x8 v = *(const bf16x8*)&Msg[row * APAD + cg * 8];
      *(bf16x8*)&msgOut[(size_t)(blk * 64 + row) * H + cg * 8] = v;
    }
  }

  // ---- coord head: silu(messages @ Wc1 + bc1) @ Wc2 ----
#pragma unroll
  for (int nt = 0; nt < 8; nt++) acc[nt] = (f32x4){0.f, 0.f, 0.f, 0.f};
  for (int ks = 0; ks < 4; ks++) {
    bf16x8 a = *(const bf16x8*)&Msg[(rowBase + l16) * APAD + ks * 32 + quad * 8];
#pragma unroll
    for (int nt = 0; nt < 8; nt++) {
      bf16x8 b = Wc1v[(nt * 4 + ks) * 64 + lane];
      acc[nt] = __builtin_amdgcn_mfma_f32_16x16x32_bf16(a, b, acc[nt], 0, 0, 0);
    }
  }
  float cwp[4] = {0.f, 0.f, 0.f, 0.f};
#pragma unroll
  for (int nt = 0; nt < 8; nt++) {
    int col = nt * 16 + l16;
    float bb = bc1s[col], w2 = wc2s[col];
#pragma unroll
    for (int reg = 0; reg < 4; reg++)
      cwp[reg] += silu_f(acc[nt][reg] + bb) * w2;
  }
#pragma unroll
  for (int reg = 0; reg < 4; reg++) {
    float s = cwp[reg];
    s += __shfl_xor(s, 1);
    s += __shfl_xor(s, 2);
    s += __shfl_xor(s, 4);
    s += __shfl_xor(s, 8);
    cwp[reg] = s;
  }
  if (l16 == 0) {
#pragma unroll
    for (int reg = 0; reg < 4; reg++) {
      int row = rowBase + quad * 4 + reg;
      size_t Rg = (size_t)blk * 64 + row;
      float inv = 1.0f / (dists[row] + 1e-8f);
      float cw = cwp[reg];
#pragma unroll
      for (int c = 0; c < 3; c++) {
        float u = cds[row * 3 + c] * inv * cw;
        if constexpr (MODE == 0) {
          atomicAdd(&coordUpd[(size_t)(batR[reg] * NA + dstR[reg]) * 3 + c],  u);
          atomicAdd(&coordUpd[(size_t)(batR[reg] * NA + srcR[reg]) * 3 + c], -u);
        } else {
          updv[Rg * 3 + c] = u;
        }
      }
    }
  }
}

// ---------------- per-atom gather (MODE 1 only) ----------------
__global__ __launch_bounds__(256, 4) void gather_kernel(
    const bf16* __restrict__ msg, const float* __restrict__ updv,
    const int* __restrict__ offsets, const int* __restrict__ degI,
    const int* __restrict__ adj, const float* __restrict__ x,
    bf16* __restrict__ aggB, float* __restrict__ xout) {
  int a = blockIdx.x;
  int tid = threadIdx.x;
  int deg = degI[a], off = offsets[a];
  int col = tid & 127, bg = tid >> 7;       // bg: batches bg*4 .. bg*4+3
  float a0 = 0.f, a1 = 0.f, a2 = 0.f, a3 = 0.f;
  for (int j = 0; j < deg; j++) {
    int ent = adj[off + j];
    int bond = ent >> 1;
    const bf16* mp = msg + ((size_t)bond * 8 + bg * 4) * H + col;
    a0 += (float)mp[0];
    a1 += (float)mp[H];
    a2 += (float)mp[2 * H];
    a3 += (float)mp[3 * H];
  }
  int b0 = bg * 4;
  aggB[((size_t)(b0 + 0) * NA + a) * H + col] = (bf16)a0;
  aggB[((size_t)(b0 + 1) * NA + a) * H + col] = (bf16)a1;
  aggB[((size_t)(b0 + 2) * NA + a) * H + col] = (bf16)a2;
  aggB[((size_t)(b0 + 3) * NA + a) * H + col] = (bf16)a3;

  if (tid < 24) {  // x finalize: 8 batches x 3 comps
    int b = tid / 3, c = tid % 3;
    float s = 0.f;
    for (int j = 0; j < deg; j++) {
      int ent = adj[off + j];
      int bond = ent >> 1;
      float sg = (ent & 1) ? 1.0f : -1.0f;   // dst:+, src:-
      s += sg * updv[((size_t)bond * 8 + b) * 3 + c];
    }
    float cnt = deg < 1 ? 1.0f : (float)deg;
    size_t i = ((size_t)b * NA + a) * 3 + c;
    xout[i] = x[i] + s / cnt;
  }
}

// ---------------- node kernel ----------------
// MODE 0: agg fp32 in d_out (in-place), fused x finalize (round-1).
// MODE 1: agg bf16 from ws, x handled by gather.
template <int MODE>
__global__ __launch_bounds__(256, 2) void node_kernel(
    const float* __restrict__ h, const float* __restrict__ x,
    const bf16* __restrict__ Wn1p, const float* __restrict__ bn1,
    const bf16* __restrict__ Wn2p, const float* __restrict__ bn2,
    const float* __restrict__ counts, const bf16* __restrict__ aggB,
    float* __restrict__ hout, float* __restrict__ xout) {
  __shared__ __align__(16) bf16 Albuf[64 * APAD];
  __shared__ __align__(16) bf16 Tbuf[64 * TPAD];
  __shared__ float bn1s[128], bn2s[128];

  const int tid = threadIdx.x, blk = blockIdx.x;
  const int g = tid >> 6, l = tid & 63;

  for (int r = g; r < 64; r += 4) {
    size_t Rg = (size_t)blk * 64 + r;   // == batch*NA + atom
    int col4 = l * 4;
    if (col4 < H) {
      float4 v = *(const float4*)(h + Rg * H + col4);
      bf16x4 t = {(bf16)v.x, (bf16)v.y, (bf16)v.z, (bf16)v.w};
      *(bf16x4*)&Albuf[r * APAD + col4] = t;
    } else if constexpr (MODE == 1) {
      *(bf16x4*)&Albuf[r * APAD + col4] =
          *(const bf16x4*)&aggB[Rg * H + (col4 - H)];
    } else {
      float4 v = *(const float4*)(hout + Rg * H + (col4 - H));
      bf16x4 t = {(bf16)v.x, (bf16)v.y, (bf16)v.z, (bf16)v.w};
      *(bf16x4*)&Albuf[r * APAD + col4] = t;
    }
  }
  if (tid < 128) { bn1s[tid] = bn1[tid]; bn2s[tid] = bn2[tid]; }
  if constexpr (MODE == 0) {
    if (tid < 192) {
      int r = tid / 3, c = tid % 3;
      size_t Rg = (size_t)blk * 64 + r;
      int a = (int)(Rg % NA);
      float cnt = counts[a];
      cnt = cnt < 1.0f ? 1.0f : cnt;
      xout[Rg * 3 + c] = x[Rg * 3 + c] + xout[Rg * 3 + c] / cnt;
    }
  }
  __syncthreads();

  const int lane = tid & 63;
  const int quad = lane >> 4, l16 = lane & 15;
  const int rowBase = (tid >> 6) * 16;
  const bf16x8* W1v = (const bf16x8*)Wn1p;
  const bf16x8* W2v = (const bf16x8*)Wn2p;

  f32x4 acc[8];
#pragma unroll
  for (int nt = 0; nt < 8; nt++) acc[nt] = (f32x4){0.f, 0.f, 0.f, 0.f};

  for (int ks = 0; ks < 8; ks++) {
    bf16x8 a = *(const bf16x8*)&Albuf[(rowBase + l16) * APAD + ks * 32 + quad * 8];
#pragma unroll
    for (int nt = 0; nt < 8; nt++) {
      bf16x8 b = W1v[(nt * 8 + ks) * 64 + lane];
      acc[nt] = __builtin_amdgcn_mfma_f32_16x16x32_bf16(a, b, acc[nt], 0, 0, 0);
    }
  }
#pragma unroll
  for (int nt = 0; nt < 8; nt++) {
    int col = nt * 16 + l16;
    float bb = bn1s[col];
#pragma unroll
    for (int reg = 0; reg < 4; reg++) {
      int row = rowBase + quad * 4 + reg;
      Tbuf[row * TPAD + col] = (bf16)silu_f(acc[nt][reg] + bb);
    }
  }

#pragma unroll
  for (int nt = 0; nt < 8; nt++) acc[nt] = (f32x4){0.f, 0.f, 0.f, 0.f};
  for (int ks = 0; ks < 4; ks++) {
    bf16x8 a = *(const bf16x8*)&Tbuf[(rowBase + l16) * TPAD + ks * 32 + quad * 8];
#pragma unroll
    for (int nt = 0; nt < 8; nt++) {
      bf16x8 b = W2v[(nt * 4 + ks) * 64 + lane];
      acc[nt] = __builtin_amdgcn_mfma_f32_16x16x32_bf16(a, b, acc[nt], 0, 0, 0);
    }
  }
#pragma unroll
  for (int nt = 0; nt < 8; nt++) {
    int col = nt * 16 + l16;
    float bb = bn2s[col];
#pragma unroll
    for (int reg = 0; reg < 4; reg++) {
      size_t Rg = (size_t)blk * 64 + rowBase + quad * 4 + reg;
      hout[Rg * H + col] = h[Rg * H + col] + acc[nt][reg] + bb;
    }
  }
}

extern "C" void kernel_launch(void* const* d_in, const int* in_sizes, int n_in,
                              void* d_out, int out_size, void* d_ws,
                              size_t ws_size, hipStream_t stream) {
  const float* h    = (const float*)d_in[0];
  const float* x    = (const float*)d_in[1];
  const int*  bonds = (const int*)d_in[2];
  const float* Wm1  = (const float*)d_in[3];
  const float* bm1  = (const float*)d_in[4];
  const float* Wm2  = (const float*)d_in[5];
  const float* bm2  = (const float*)d_in[6];
  const float* Wn1  = (const float*)d_in[7];
  const float* bn1  = (const float*)d_in[8];
  const float* Wn2  = (const float*)d_in[9];
  const float* bn2  = (const float*)d_in[10];
  const float* Wc1  = (const float*)d_in[11];
  const float* bc1  = (const float*)d_in[12];
  const float* Wc2  = (const float*)d_in[13];

  float* out = (float*)d_out;
  float* hout = out;
  float* xout = out + (size_t)NBATCH * NA * H;

  char* ws = (char*)d_ws;

  // big layout
  const size_t OFF_DEG   = 0;                       // NA int
  const size_t OFF_OFFS  = 81920;                   // NA int
  const size_t OFF_CUR   = 163840;                  // NA int
  const size_t OFF_ADJ   = 245760;                  // 2*NB int = 480000
  const size_t OFF_W1    = 786432;                  // bf16 weights
  const size_t OFF_W2    = OFF_W1 + 65536;
  const size_t OFF_WN1   = OFF_W2 + 32768;
  const size_t OFF_WN2   = OFF_WN1 + 65536;
  const size_t OFF_WC1   = OFF_WN2 + 32768;
  const size_t OFF_UPDV  = 1048576;                 // NB*8*3 f32 = 5760000
  const size_t OFF_MSG   = 8388608;                 // NB*8*128 bf16 = 122880000
  const size_t OFF_AGG   = 132120576;               // NA*8*128 bf16 = 40960000
  const size_t NEED      = OFF_AGG + (size_t)NA * 8 * H * 2;  // 173,080,576

  if (ws_size >= NEED) {
    int*  degI  = (int*)(ws + OFF_DEG);
    int*  offs  = (int*)(ws + OFF_OFFS);
    int*  cur   = (int*)(ws + OFF_CUR);
    int*  adj   = (int*)(ws + OFF_ADJ);
    bf16* W1p   = (bf16*)(ws + OFF_W1);
    bf16* W2p   = (bf16*)(ws + OFF_W2);
    bf16* Wn1p  = (bf16*)(ws + OFF_WN1);
    bf16* Wn2p  = (bf16*)(ws + OFF_WN2);
    bf16* Wc1p  = (bf16*)(ws + OFF_WC1);
    float* updv = (float*)(ws + OFF_UPDV);
    bf16* msgB  = (bf16*)(ws + OFF_MSG);
    bf16* aggB  = (bf16*)(ws + OFF_AGG);

    hipMemsetAsync(degI, 0, NA * sizeof(int), stream);
    hipMemsetAsync(cur, 0, NA * sizeof(int), stream);

    pack_w<<<128, 256, 0, stream>>>(Wm1, W1p, 256);
    pack_w<<<64, 256, 0, stream>>>(Wm2, W2p, 128);
    pack_w<<<128, 256, 0, stream>>>(Wn1, Wn1p, 256);
    pack_w<<<64, 256, 0, stream>>>(Wn2, Wn2p, 128);
    pack_w<<<64, 256, 0, stream>>>(Wc1, Wc1p, 128);

    count_deg<<<(NB + 255) / 256, 256, 0, stream>>>(bonds, degI);
    scan_offsets<<<1, 1024, 0, stream>>>(degI, offs);
    build_adj<<<(NB + 255) / 256, 256, 0, stream>>>(bonds, offs, cur, adj);

    msg_kernel<1><<<NB * NBATCH / 64, 256, 0, stream>>>(
        h, x, bonds, W1p, bm1, W2p, bm2, Wm1 + 256 * H, Wc1p, bc1, Wc2,
        nullptr, nullptr, msgB, updv);
    gather_kernel<<<NA, 256, 0, stream>>>(msgB, updv, offs, degI, adj, x,
                                          aggB, xout);
    node_kernel<1><<<NBATCH * NA / 64, 256, 0, stream>>>(
        h, x, Wn1p, bn1, Wn2p, bn2, nullptr, aggB, hout, xout);
  } else {
    // fallback: round-1 atomic path (small ws)
    float* counts = (float*)ws;                 // 20000 f32
    bf16* W1p  = (bf16*)(ws + 81920);
    bf16* W2p  = (bf16*)(ws + 147456);
    bf16* Wn1p = (bf16*)(ws + 180224);
    bf16* Wn2p = (bf16*)(ws + 245760);
    bf16* Wc1p = (bf16*)(ws + 278528);

    hipMemsetAsync(d_out, 0, (size_t)out_size * sizeof(float), stream);
    hipMemsetAsync(counts, 0, NA * sizeof(float), stream);

    pack_w<<<128, 256, 0, stream>>>(Wm1, W1p, 256);
    pack_w<<<64, 256, 0, stream>>>(Wm2, W2p, 128);
    pack_w<<<128, 256, 0, stream>>>(Wn1, Wn1p, 256);
    pack_w<<<64, 256, 0, stream>>>(Wn2, Wn2p, 128);
    pack_w<<<64, 256, 0, stream>>>(Wc1, Wc1p, 128);
    bond_counts<<<(NB + 255) / 256, 256, 0, stream>>>(bonds, counts);

    msg_kernel<0><<<NB * NBATCH / 64, 256, 0, stream>>>(
        h, x, bonds, W1p, bm1, W2p, bm2, Wm1 + 256 * H, Wc1p, bc1, Wc2,
        hout, xout, nullptr, nullptr);
    node_kernel<0><<<NBATCH * NA / 64, 256, 0, stream>>>(
        h, x, Wn1p, bn1, Wn2p, bn2, counts, nullptr, hout, xout);
  }
}

// Round 4
// 652.665 us; speedup vs baseline: 1.4484x; 1.2128x over previous
//
#include <hip/hip_runtime.h>

// BondAwareEGNN fused layer — round 4 (= round 3 with compile fix:
// removed dead `bf16x2* hi;` declaration in gather_kernel).
//
// Round-2 post-mortem: msg_kernel 473us, MfmaUtil 5.5%, VALUBusy 28%,
// HBM 11%, Occupancy 22% -> latency-bound: 2 blocks/CU (LDS 54.8KB),
// fp32 gather + cvt + LDS staging + barrier dominate.
//
// Structure:
//   cast_h      : h fp32 -> hb bf16 (ws, 41MB), coalesced.
//   pack_w x5   : weights -> bf16 fragment-linear.
//   CSR build   : count/scan/fill (proven).
//   msg_kernel  : NO A-staging LDS. Each lane loads its MFMA A-fragment
//                 directly from hb[src]/hb[dst] (bf16x8 = 16B). LDS only for
//                 t1/msg transpose (2x 17.4KB) + dists/biases. One barrier.
//                 4 blocks/CU.
//   gather      : vector loads; agg -> d_out h-region as fp32;
//                 x_out finalized here.
//   node_kernel : register-direct A-frags (hb bf16 + agg fp32->bf16),
//                 LDS = Tbuf only, zero barriers; h_out in place over agg.
//
// ws NEED = 170,655,744 B < 173,080,576 B proven available in round 2.

#define H      128
#define NA     20000
#define NB     60000
#define NBATCH 8

#define TPAD 136   // 128 + 8 bf16

typedef __bf16 bf16;
typedef __bf16 bf16x4 __attribute__((ext_vector_type(4)));
typedef __bf16 bf16x8 __attribute__((ext_vector_type(8)));
typedef float  f32x4  __attribute__((ext_vector_type(4)));

__device__ __forceinline__ float silu_f(float v) {
  return v / (1.0f + __expf(-v));
}

__global__ void cast_h(const float* __restrict__ src, bf16* __restrict__ dst) {
  int i = blockIdx.x * 256 + threadIdx.x;  // one float4 per thread
  float4 v = *(const float4*)(src + (size_t)i * 4);
  bf16x4 t = {(bf16)v.x, (bf16)v.y, (bf16)v.z, (bf16)v.w};
  *(bf16x4*)(dst + (size_t)i * 4) = t;
}

// fp32 KxN(128) row-major -> bf16 fragment-linear (8 bf16 per lane-frag).
__global__ void pack_w(const float* __restrict__ src, bf16* __restrict__ dst,
                       int K) {
  int i = blockIdx.x * 256 + threadIdx.x;
  if (i >= K * 128) return;
  int k = i >> 7, n = i & 127;
  int nt = n >> 4, ks = k >> 5;
  int lane = (((k >> 3) & 3) << 4) | (n & 15);
  int j = k & 7;
  int KS = K >> 5;
  dst[((((nt * KS + ks) * 64) + lane) << 3) + j] = (bf16)src[i];
}

// ---------------- CSR build ----------------
__global__ void count_deg(const int* __restrict__ bonds,
                          int* __restrict__ degI) {
  int e = blockIdx.x * 256 + threadIdx.x;
  if (e >= NB) return;
  atomicAdd(&degI[bonds[2 * e]], 1);
  atomicAdd(&degI[bonds[2 * e + 1]], 1);
}

__global__ void scan_offsets(const int* __restrict__ deg,
                             int* __restrict__ offsets) {
  __shared__ int sh[1024];
  __shared__ int carry;
  int tid = threadIdx.x;
  if (tid == 0) carry = 0;
  __syncthreads();
  for (int base = 0; base < NA; base += 1024) {
    int i = base + tid;
    int v = (i < NA) ? deg[i] : 0;
    sh[tid] = v;
    __syncthreads();
    for (int ofs = 1; ofs < 1024; ofs <<= 1) {
      int t = (tid >= ofs) ? sh[tid - ofs] : 0;
      __syncthreads();
      sh[tid] += t;
      __syncthreads();
    }
    int incl = sh[tid];
    int c = carry;
    if (i < NA) offsets[i] = incl - v + c;  // exclusive
    __syncthreads();
    if (tid == 1023) carry = c + sh[1023];
    __syncthreads();
  }
}

__global__ void build_adj(const int* __restrict__ bonds,
                          const int* __restrict__ offsets,
                          int* __restrict__ cursor, int* __restrict__ adj) {
  int e = blockIdx.x * 256 + threadIdx.x;
  if (e >= NB) return;
  int s = bonds[2 * e], d = bonds[2 * e + 1];
  int p = atomicAdd(&cursor[s], 1);
  adj[offsets[s] + p] = (e << 1);        // src endpoint (coord sign -)
  p = atomicAdd(&cursor[d], 1);
  adj[offsets[d] + p] = (e << 1) | 1;    // dst endpoint (coord sign +)
}

// ---------------- message kernel ----------------
__global__ __launch_bounds__(256, 4) void msg_kernel(
    const bf16* __restrict__ hb, const float* __restrict__ x,
    const int* __restrict__ bonds,
    const bf16* __restrict__ W1p, const float* __restrict__ bm1,
    const bf16* __restrict__ W2p, const float* __restrict__ bm2,
    const float* __restrict__ w1c,   // Wm1 row 256 (dist row), fp32[128]
    const bf16* __restrict__ Wc1p, const float* __restrict__ bc1,
    const float* __restrict__ Wc2,
    bf16* __restrict__ msgOut, float* __restrict__ updv) {
  __shared__ __align__(16) bf16 Tbuf[64 * TPAD];
  __shared__ __align__(16) bf16 MsgB[64 * TPAD];
  __shared__ float cds[64 * 3];
  __shared__ float dists[64];
  __shared__ float bm1s[128], bm2s[128], w1cs[128], bc1s[128], wc2s[128];

  const int tid = threadIdx.x, blk = blockIdx.x;

  if (tid < 64) {
    int Rg = blk * 64 + tid;
    int bond = Rg >> 3, batch = Rg & 7;
    int s = bonds[2 * bond], dn = bonds[2 * bond + 1];
    const float* xs = x + (size_t)(batch * NA + s) * 3;
    const float* xd = x + (size_t)(batch * NA + dn) * 3;
    float c0 = xd[0] - xs[0], c1 = xd[1] - xs[1], c2 = xd[2] - xs[2];
    cds[tid * 3 + 0] = c0; cds[tid * 3 + 1] = c1; cds[tid * 3 + 2] = c2;
    dists[tid] = sqrtf(c0 * c0 + c1 * c1 + c2 * c2);
  }
  if (tid < 128) {
    bm1s[tid] = bm1[tid]; bm2s[tid] = bm2[tid]; w1cs[tid] = w1c[tid];
    bc1s[tid] = bc1[tid]; wc2s[tid] = Wc2[tid];
  }
  __syncthreads();   // the ONLY barrier

  const int lane = tid & 63;
  const int quad = lane >> 4, l16 = lane & 15;
  const int rowBase = (tid >> 6) * 16;
  const bf16x8* W1v = (const bf16x8*)W1p;
  const bf16x8* W2v = (const bf16x8*)W2p;
  const bf16x8* Wc1v = (const bf16x8*)Wc1p;

  // per-lane A-row metadata (row = rowBase + l16)
  const int RgA = blk * 64 + rowBase + l16;
  const int bondA = RgA >> 3, batA = RgA & 7;
  const int sA = bonds[2 * bondA], dA = bonds[2 * bondA + 1];
  const bf16* hsrc = hb + (size_t)(batA * NA + sA) * H;
  const bf16* hdst = hb + (size_t)(batA * NA + dA) * H;

  f32x4 acc[8];
#pragma unroll
  for (int nt = 0; nt < 8; nt++) acc[nt] = (f32x4){0.f, 0.f, 0.f, 0.f};

  // ---- layer 1: K = 256, A-fragments straight from global ----
#pragma unroll
  for (int ks = 0; ks < 4; ks++) {
    bf16x8 a = *(const bf16x8*)(hsrc + ks * 32 + quad * 8);
#pragma unroll
    for (int nt = 0; nt < 8; nt++) {
      bf16x8 b = W1v[(nt * 8 + ks) * 64 + lane];
      acc[nt] = __builtin_amdgcn_mfma_f32_16x16x32_bf16(a, b, acc[nt], 0, 0, 0);
    }
  }
#pragma unroll
  for (int ks = 4; ks < 8; ks++) {
    bf16x8 a = *(const bf16x8*)(hdst + (ks - 4) * 32 + quad * 8);
#pragma unroll
    for (int nt = 0; nt < 8; nt++) {
      bf16x8 b = W1v[(nt * 8 + ks) * 64 + lane];
      acc[nt] = __builtin_amdgcn_mfma_f32_16x16x32_bf16(a, b, acc[nt], 0, 0, 0);
    }
  }
  // t1 epilogue -> Tbuf (each wave touches only its own 16 rows: no barrier)
#pragma unroll
  for (int nt = 0; nt < 8; nt++) {
    int col = nt * 16 + l16;
    float bb = bm1s[col], wc = w1cs[col];
#pragma unroll
    for (int reg = 0; reg < 4; reg++) {
      int row = rowBase + quad * 4 + reg;
      float v = acc[nt][reg] + bb + dists[row] * wc;
      Tbuf[row * TPAD + col] = (bf16)silu_f(v);
    }
  }

  // ---- layer 2: K = 128 -> messages ----
#pragma unroll
  for (int nt = 0; nt < 8; nt++) acc[nt] = (f32x4){0.f, 0.f, 0.f, 0.f};
#pragma unroll
  for (int ks = 0; ks < 4; ks++) {
    bf16x8 a = *(const bf16x8*)&Tbuf[(rowBase + l16) * TPAD + ks * 32 + quad * 8];
#pragma unroll
    for (int nt = 0; nt < 8; nt++) {
      bf16x8 b = W2v[(nt * 4 + ks) * 64 + lane];
      acc[nt] = __builtin_amdgcn_mfma_f32_16x16x32_bf16(a, b, acc[nt], 0, 0, 0);
    }
  }
#pragma unroll
  for (int nt = 0; nt < 8; nt++) {
    int col = nt * 16 + l16;
    float bb = bm2s[col];
#pragma unroll
    for (int reg = 0; reg < 4; reg++) {
      int row = rowBase + quad * 4 + reg;
      MsgB[row * TPAD + col] = (bf16)silu_f(acc[nt][reg] + bb);
    }
  }

  // ---- coord head: silu(messages @ Wc1 + bc1) @ Wc2 ----
#pragma unroll
  for (int nt = 0; nt < 8; nt++) acc[nt] = (f32x4){0.f, 0.f, 0.f, 0.f};
#pragma unroll
  for (int ks = 0; ks < 4; ks++) {
    bf16x8 a = *(const bf16x8*)&MsgB[(rowBase + l16) * TPAD + ks * 32 + quad * 8];
#pragma unroll
    for (int nt = 0; nt < 8; nt++) {
      bf16x8 b = Wc1v[(nt * 4 + ks) * 64 + lane];
      acc[nt] = __builtin_amdgcn_mfma_f32_16x16x32_bf16(a, b, acc[nt], 0, 0, 0);
    }
  }

  // copy this wave's 16 message rows to global (coalesced 16B chunks)
#pragma unroll
  for (int i = 0; i < 4; i++) {
    int idx = i * 64 + lane;
    int row = rowBase + (idx >> 4), cg = idx & 15;
    *(bf16x8*)&msgOut[(size_t)(blk * 64 + row) * H + cg * 8] =
        *(const bf16x8*)&MsgB[row * TPAD + cg * 8];
  }

  float cwp[4] = {0.f, 0.f, 0.f, 0.f};
#pragma unroll
  for (int nt = 0; nt < 8; nt++) {
    int col = nt * 16 + l16;
    float bb = bc1s[col], w2 = wc2s[col];
#pragma unroll
    for (int reg = 0; reg < 4; reg++)
      cwp[reg] += silu_f(acc[nt][reg] + bb) * w2;
  }
#pragma unroll
  for (int reg = 0; reg < 4; reg++) {
    float s = cwp[reg];
    s += __shfl_xor(s, 1);
    s += __shfl_xor(s, 2);
    s += __shfl_xor(s, 4);
    s += __shfl_xor(s, 8);
    cwp[reg] = s;
  }
  if (l16 == 0) {
#pragma unroll
    for (int reg = 0; reg < 4; reg++) {
      int row = rowBase + quad * 4 + reg;
      size_t Rg = (size_t)blk * 64 + row;
      float inv = 1.0f / (dists[row] + 1e-8f);
      float cw = cwp[reg];
#pragma unroll
      for (int c = 0; c < 3; c++)
        updv[Rg * 3 + c] = cds[row * 3 + c] * inv * cw;
    }
  }
}

// ---------------- per-atom gather ----------------
// agg (fp32) -> d_out h region; x_out finalized here.
__global__ __launch_bounds__(256, 4) void gather_kernel(
    const bf16* __restrict__ msg, const float* __restrict__ updv,
    const int* __restrict__ offsets, const int* __restrict__ degI,
    const int* __restrict__ adj, const float* __restrict__ x,
    float* __restrict__ agg, float* __restrict__ xout) {
  int a = blockIdx.x;
  int tid = threadIdx.x;
  int deg = degI[a], off = offsets[a];
  int c2 = tid & 63;        // column pair: cols c2*2, c2*2+1
  int bg = tid >> 6;        // batch pair: batches bg*2, bg*2+1
  float2 a0 = {0.f, 0.f}, a1 = {0.f, 0.f};
  for (int j = 0; j < deg; j++) {
    int ent = adj[off + j];
    int bond = ent >> 1;
    const bf16* mp = msg + ((size_t)bond * 8 + bg * 2) * H + c2 * 2;
    const ushort2 u0 = *(const ushort2*)mp;
    const ushort2 u1 = *(const ushort2*)(mp + H);
    union { unsigned short u; bf16 b; } t;
    t.u = u0.x; a0.x += (float)t.b;
    t.u = u0.y; a0.y += (float)t.b;
    t.u = u1.x; a1.x += (float)t.b;
    t.u = u1.y; a1.y += (float)t.b;
  }
  int b0 = bg * 2;
  *(float2*)&agg[((size_t)(b0 + 0) * NA + a) * H + c2 * 2] = a0;
  *(float2*)&agg[((size_t)(b0 + 1) * NA + a) * H + c2 * 2] = a1;

  if (tid < 24) {  // x finalize: 8 batches x 3 comps
    int b = tid / 3, c = tid % 3;
    float s = 0.f;
    for (int j = 0; j < deg; j++) {
      int ent = adj[off + j];
      int bond = ent >> 1;
      float sg = (ent & 1) ? 1.0f : -1.0f;   // dst:+, src:-
      s += sg * updv[((size_t)bond * 8 + b) * 3 + c];
    }
    float cnt = deg < 1 ? 1.0f : (float)deg;
    size_t i = ((size_t)b * NA + a) * 3 + c;
    xout[i] = x[i] + s / cnt;
  }
}

// ---------------- node kernel ----------------
// Register-direct A-frags; agg fp32 read from d_out h-region, h_out written
// in place. Zero barriers; each wave owns its 16 rows end-to-end.
__global__ __launch_bounds__(256, 4) void node_kernel(
    const float* __restrict__ h, const bf16* __restrict__ hb,
    const bf16* __restrict__ Wn1p, const float* __restrict__ bn1,
    const bf16* __restrict__ Wn2p, const float* __restrict__ bn2,
    float* __restrict__ hout) {
  __shared__ __align__(16) bf16 Tbuf[64 * TPAD];

  const int tid = threadIdx.x, blk = blockIdx.x;
  const int lane = tid & 63;
  const int quad = lane >> 4, l16 = lane & 15;
  const int rowBase = (tid >> 6) * 16;

  const size_t RgA = (size_t)blk * 64 + rowBase + l16;
  const bf16* hrow = hb + RgA * H;
  const float* arow = hout + RgA * H;   // aggregated (fp32), read-only phase
  const bf16x8* W1v = (const bf16x8*)Wn1p;
  const bf16x8* W2v = (const bf16x8*)Wn2p;

  f32x4 acc[8];
#pragma unroll
  for (int nt = 0; nt < 8; nt++) acc[nt] = (f32x4){0.f, 0.f, 0.f, 0.f};

  // layer 1: K=256 = [h (bf16) | agg (fp32->bf16)]
#pragma unroll
  for (int ks = 0; ks < 4; ks++) {
    bf16x8 a = *(const bf16x8*)(hrow + ks * 32 + quad * 8);
#pragma unroll
    for (int nt = 0; nt < 8; nt++) {
      bf16x8 b = W1v[(nt * 8 + ks) * 64 + lane];
      acc[nt] = __builtin_amdgcn_mfma_f32_16x16x32_bf16(a, b, acc[nt], 0, 0, 0);
    }
  }
#pragma unroll
  for (int ks = 4; ks < 8; ks++) {
    float4 f0 = *(const float4*)(arow + (ks - 4) * 32 + quad * 8);
    float4 f1 = *(const float4*)(arow + (ks - 4) * 32 + quad * 8 + 4);
    bf16x8 a = {(bf16)f0.x, (bf16)f0.y, (bf16)f0.z, (bf16)f0.w,
                (bf16)f1.x, (bf16)f1.y, (bf16)f1.z, (bf16)f1.w};
#pragma unroll
    for (int nt = 0; nt < 8; nt++) {
      bf16x8 b = W1v[(nt * 8 + ks) * 64 + lane];
      acc[nt] = __builtin_amdgcn_mfma_f32_16x16x32_bf16(a, b, acc[nt], 0, 0, 0);
    }
  }
#pragma unroll
  for (int nt = 0; nt < 8; nt++) {
    int col = nt * 16 + l16;
    float bb = bn1[col];
#pragma unroll
    for (int reg = 0; reg < 4; reg++) {
      int row = rowBase + quad * 4 + reg;
      Tbuf[row * TPAD + col] = (bf16)silu_f(acc[nt][reg] + bb);
    }
  }

#pragma unroll
  for (int nt = 0; nt < 8; nt++) acc[nt] = (f32x4){0.f, 0.f, 0.f, 0.f};
#pragma unroll
  for (int ks = 0; ks < 4; ks++) {
    bf16x8 a = *(const bf16x8*)&Tbuf[(rowBase + l16) * TPAD + ks * 32 + quad * 8];
#pragma unroll
    for (int nt = 0; nt < 8; nt++) {
      bf16x8 b = W2v[(nt * 4 + ks) * 64 + lane];
      acc[nt] = __builtin_amdgcn_mfma_f32_16x16x32_bf16(a, b, acc[nt], 0, 0, 0);
    }
  }
#pragma unroll
  for (int nt = 0; nt < 8; nt++) {
    int col = nt * 16 + l16;
    float bb = bn2[col];
#pragma unroll
    for (int reg = 0; reg < 4; reg++) {
      size_t Rg = (size_t)blk * 64 + rowBase + quad * 4 + reg;
      hout[Rg * H + col] = h[Rg * H + col] + acc[nt][reg] + bb;
    }
  }
}

extern "C" void kernel_launch(void* const* d_in, const int* in_sizes, int n_in,
                              void* d_out, int out_size, void* d_ws,
                              size_t ws_size, hipStream_t stream) {
  const float* h    = (const float*)d_in[0];
  const float* x    = (const float*)d_in[1];
  const int*  bonds = (const int*)d_in[2];
  const float* Wm1  = (const float*)d_in[3];
  const float* bm1  = (const float*)d_in[4];
  const float* Wm2  = (const float*)d_in[5];
  const float* bm2  = (const float*)d_in[6];
  const float* Wn1  = (const float*)d_in[7];
  const float* bn1  = (const float*)d_in[8];
  const float* Wn2  = (const float*)d_in[9];
  const float* bn2  = (const float*)d_in[10];
  const float* Wc1  = (const float*)d_in[11];
  const float* bc1  = (const float*)d_in[12];
  const float* Wc2  = (const float*)d_in[13];

  float* out  = (float*)d_out;
  float* hout = out;                                // agg (fp32) then h_out
  float* xout = out + (size_t)NBATCH * NA * H;

  char* ws = (char*)d_ws;
  // layout (bytes): ws_size >= 173,080,576 proven (round-2 big path ran);
  // NEED here = 170,655,744.
  const size_t OFF_DEG  = 0;                        // NA int
  const size_t OFF_OFFS = 81920;                    // NA int
  const size_t OFF_CUR  = 163840;                   // NA int
  const size_t OFF_ADJ  = 245760;                   // 2*NB int = 480,000 B
  const size_t OFF_W1   = 786432;                   // 65,536 B
  const size_t OFF_W2   = OFF_W1 + 65536;           // 32,768
  const size_t OFF_WN1  = OFF_W2 + 32768;           // 65,536
  const size_t OFF_WN2  = OFF_WN1 + 65536;          // 32,768
  const size_t OFF_WC1  = OFF_WN2 + 32768;          // 32,768 (ends 1,015,808)
  const size_t OFF_UPDV = 1048576;                  // NB*8*3 f32 = 5,760,000
  const size_t OFF_HB   = 6815744;                  // 160000*128 bf16 = 40,960,000
  const size_t OFF_MSG  = 47775744;                 // NB*8*128 bf16 = 122,880,000
                                                    // end: 170,655,744

  int*   degI = (int*)(ws + OFF_DEG);
  int*   offs = (int*)(ws + OFF_OFFS);
  int*   cur  = (int*)(ws + OFF_CUR);
  int*   adj  = (int*)(ws + OFF_ADJ);
  bf16*  W1p  = (bf16*)(ws + OFF_W1);
  bf16*  W2p  = (bf16*)(ws + OFF_W2);
  bf16*  Wn1p = (bf16*)(ws + OFF_WN1);
  bf16*  Wn2p = (bf16*)(ws + OFF_WN2);
  bf16*  Wc1p = (bf16*)(ws + OFF_WC1);
  float* updv = (float*)(ws + OFF_UPDV);
  bf16*  hb   = (bf16*)(ws + OFF_HB);
  bf16*  msgB = (bf16*)(ws + OFF_MSG);

  (void)hipMemsetAsync(degI, 0, NA * sizeof(int), stream);
  (void)hipMemsetAsync(cur, 0, NA * sizeof(int), stream);

  cast_h<<<NBATCH * NA * H / 1024, 256, 0, stream>>>(h, hb);
  pack_w<<<128, 256, 0, stream>>>(Wm1, W1p, 256);
  pack_w<<<64, 256, 0, stream>>>(Wm2, W2p, 128);
  pack_w<<<128, 256, 0, stream>>>(Wn1, Wn1p, 256);
  pack_w<<<64, 256, 0, stream>>>(Wn2, Wn2p, 128);
  pack_w<<<64, 256, 0, stream>>>(Wc1, Wc1p, 128);

  count_deg<<<(NB + 255) / 256, 256, 0, stream>>>(bonds, degI);
  scan_offsets<<<1, 1024, 0, stream>>>(degI, offs);
  build_adj<<<(NB + 255) / 256, 256, 0, stream>>>(bonds, offs, cur, adj);

  msg_kernel<<<NB * NBATCH / 64, 256, 0, stream>>>(
      hb, x, bonds, W1p, bm1, W2p, bm2, Wm1 + 256 * H, Wc1p, bc1, Wc2,
      msgB, updv);
  gather_kernel<<<NA, 256, 0, stream>>>(msgB, updv, offs, degI, adj, x,
                                        hout, xout);
  node_kernel<<<NBATCH * NA / 64, 256, 0, stream>>>(
      h, hb, Wn1p, bn1, Wn2p, bn2, hout);
}

// Round 5
// 644.685 us; speedup vs baseline: 1.4663x; 1.0124x over previous
//
#include <hip/hip_runtime.h>

// BondAwareEGNN fused layer — round 5.
//
// Round-4 post-mortem: msg 286us VALU-bound (37% VALU vs 9% MFMA: silu's
// full-precision fp32 divide ~10 inst x 96/lane). gather+node round-trip
// 82MB fp32 agg through d_out + 245MB msg re-read.
//
// Round-5 changes:
//   1. silu via __builtin_amdgcn_rcpf (1-ulp) — kills the div sequence.
//   2. gather fused INTO node_kernel: each lane accumulates its MFMA
//      A-fragment for `aggregated` register-direct from msgB via CSR
//      (fp32 acc over deg incident 16B chunks). No agg buffer at all.
//   3. x_out via tiny x_kernel (signed updv sum / deg).
//   4. scan_offsets rewritten with wave-shfl scans (4 barriers/chunk).

#define H      128
#define NA     20000
#define NB     60000
#define NBATCH 8

#define TPAD 136   // 128 + 8 bf16

typedef __bf16 bf16;
typedef __bf16 bf16x4 __attribute__((ext_vector_type(4)));
typedef __bf16 bf16x8 __attribute__((ext_vector_type(8)));
typedef float  f32x4  __attribute__((ext_vector_type(4)));

__device__ __forceinline__ float silu_f(float v) {
  float e = __expf(-v);
  return v * __builtin_amdgcn_rcpf(1.0f + e);  // 1-ulp rcp; inf -> 0 ok
}

__global__ void cast_h(const float* __restrict__ src, bf16* __restrict__ dst) {
  int i = blockIdx.x * 256 + threadIdx.x;  // one float4 per thread
  float4 v = *(const float4*)(src + (size_t)i * 4);
  bf16x4 t = {(bf16)v.x, (bf16)v.y, (bf16)v.z, (bf16)v.w};
  *(bf16x4*)(dst + (size_t)i * 4) = t;
}

// fp32 KxN(128) row-major -> bf16 fragment-linear (8 bf16 per lane-frag).
__global__ void pack_w(const float* __restrict__ src, bf16* __restrict__ dst,
                       int K) {
  int i = blockIdx.x * 256 + threadIdx.x;
  if (i >= K * 128) return;
  int k = i >> 7, n = i & 127;
  int nt = n >> 4, ks = k >> 5;
  int lane = (((k >> 3) & 3) << 4) | (n & 15);
  int j = k & 7;
  int KS = K >> 5;
  dst[((((nt * KS + ks) * 64) + lane) << 3) + j] = (bf16)src[i];
}

// ---------------- CSR build ----------------
__global__ void count_deg(const int* __restrict__ bonds,
                          int* __restrict__ degI) {
  int e = blockIdx.x * 256 + threadIdx.x;
  if (e >= NB) return;
  atomicAdd(&degI[bonds[2 * e]], 1);
  atomicAdd(&degI[bonds[2 * e + 1]], 1);
}

// single block, 1024 threads, wave-shfl scan (4 barriers per 1024-chunk)
__global__ void scan_offsets(const int* __restrict__ deg,
                             int* __restrict__ offsets) {
  __shared__ int wsum[16];
  __shared__ int carry;
  const int tid = threadIdx.x;
  const int wave = tid >> 6, lane = tid & 63;
  if (tid == 0) carry = 0;
  __syncthreads();
  for (int base = 0; base < NA; base += 1024) {
    int i = base + tid;
    int v = (i < NA) ? deg[i] : 0;
    int s = v;  // inclusive scan within wave
#pragma unroll
    for (int o = 1; o < 64; o <<= 1) {
      int t = __shfl_up(s, o);
      if (lane >= o) s += t;
    }
    if (lane == 63) wsum[wave] = s;
    __syncthreads();
    if (wave == 0) {  // scan the 16 wave totals
      int w = (lane < 16) ? wsum[lane] : 0;
#pragma unroll
      for (int o = 1; o < 16; o <<= 1) {
        int t = __shfl_up(w, o);
        if (lane >= o) w += t;
      }
      if (lane < 16) wsum[lane] = w;  // inclusive
    }
    __syncthreads();
    int pre = carry + (wave > 0 ? wsum[wave - 1] : 0);
    if (i < NA) offsets[i] = pre + s - v;  // exclusive
    __syncthreads();
    if (tid == 0) carry += wsum[15];
    __syncthreads();
  }
}

__global__ void build_adj(const int* __restrict__ bonds,
                          const int* __restrict__ offsets,
                          int* __restrict__ cursor, int* __restrict__ adj) {
  int e = blockIdx.x * 256 + threadIdx.x;
  if (e >= NB) return;
  int s = bonds[2 * e], d = bonds[2 * e + 1];
  int p = atomicAdd(&cursor[s], 1);
  adj[offsets[s] + p] = (e << 1);        // src endpoint (coord sign -)
  p = atomicAdd(&cursor[d], 1);
  adj[offsets[d] + p] = (e << 1) | 1;    // dst endpoint (coord sign +)
}

// ---------------- message kernel ----------------
__global__ __launch_bounds__(256, 4) void msg_kernel(
    const bf16* __restrict__ hb, const float* __restrict__ x,
    const int* __restrict__ bonds,
    const bf16* __restrict__ W1p, const float* __restrict__ bm1,
    const bf16* __restrict__ W2p, const float* __restrict__ bm2,
    const float* __restrict__ w1c,   // Wm1 row 256 (dist row), fp32[128]
    const bf16* __restrict__ Wc1p, const float* __restrict__ bc1,
    const float* __restrict__ Wc2,
    bf16* __restrict__ msgOut, float* __restrict__ updv) {
  __shared__ __align__(16) bf16 Tbuf[64 * TPAD];
  __shared__ __align__(16) bf16 MsgB[64 * TPAD];
  __shared__ float cds[64 * 3];
  __shared__ float dists[64];
  __shared__ float bm1s[128], bm2s[128], w1cs[128], bc1s[128], wc2s[128];

  const int tid = threadIdx.x, blk = blockIdx.x;

  if (tid < 64) {
    int Rg = blk * 64 + tid;
    int bond = Rg >> 3, batch = Rg & 7;
    int s = bonds[2 * bond], dn = bonds[2 * bond + 1];
    const float* xs = x + (size_t)(batch * NA + s) * 3;
    const float* xd = x + (size_t)(batch * NA + dn) * 3;
    float c0 = xd[0] - xs[0], c1 = xd[1] - xs[1], c2 = xd[2] - xs[2];
    cds[tid * 3 + 0] = c0; cds[tid * 3 + 1] = c1; cds[tid * 3 + 2] = c2;
    dists[tid] = sqrtf(c0 * c0 + c1 * c1 + c2 * c2);
  }
  if (tid < 128) {
    bm1s[tid] = bm1[tid]; bm2s[tid] = bm2[tid]; w1cs[tid] = w1c[tid];
    bc1s[tid] = bc1[tid]; wc2s[tid] = Wc2[tid];
  }
  __syncthreads();   // the ONLY barrier

  const int lane = tid & 63;
  const int quad = lane >> 4, l16 = lane & 15;
  const int rowBase = (tid >> 6) * 16;
  const bf16x8* W1v = (const bf16x8*)W1p;
  const bf16x8* W2v = (const bf16x8*)W2p;
  const bf16x8* Wc1v = (const bf16x8*)Wc1p;

  // per-lane A-row metadata (row = rowBase + l16)
  const int RgA = blk * 64 + rowBase + l16;
  const int bondA = RgA >> 3, batA = RgA & 7;
  const int sA = bonds[2 * bondA], dA = bonds[2 * bondA + 1];
  const bf16* hsrc = hb + (size_t)(batA * NA + sA) * H;
  const bf16* hdst = hb + (size_t)(batA * NA + dA) * H;

  f32x4 acc[8];
#pragma unroll
  for (int nt = 0; nt < 8; nt++) acc[nt] = (f32x4){0.f, 0.f, 0.f, 0.f};

  // ---- layer 1: K = 256, A-fragments straight from global ----
#pragma unroll
  for (int ks = 0; ks < 4; ks++) {
    bf16x8 a = *(const bf16x8*)(hsrc + ks * 32 + quad * 8);
#pragma unroll
    for (int nt = 0; nt < 8; nt++) {
      bf16x8 b = W1v[(nt * 8 + ks) * 64 + lane];
      acc[nt] = __builtin_amdgcn_mfma_f32_16x16x32_bf16(a, b, acc[nt], 0, 0, 0);
    }
  }
#pragma unroll
  for (int ks = 4; ks < 8; ks++) {
    bf16x8 a = *(const bf16x8*)(hdst + (ks - 4) * 32 + quad * 8);
#pragma unroll
    for (int nt = 0; nt < 8; nt++) {
      bf16x8 b = W1v[(nt * 8 + ks) * 64 + lane];
      acc[nt] = __builtin_amdgcn_mfma_f32_16x16x32_bf16(a, b, acc[nt], 0, 0, 0);
    }
  }
  // t1 epilogue -> Tbuf (each wave touches only its own 16 rows: no barrier)
#pragma unroll
  for (int nt = 0; nt < 8; nt++) {
    int col = nt * 16 + l16;
    float bb = bm1s[col], wc = w1cs[col];
#pragma unroll
    for (int reg = 0; reg < 4; reg++) {
      int row = rowBase + quad * 4 + reg;
      float v = acc[nt][reg] + bb + dists[row] * wc;
      Tbuf[row * TPAD + col] = (bf16)silu_f(v);
    }
  }

  // ---- layer 2: K = 128 -> messages ----
#pragma unroll
  for (int nt = 0; nt < 8; nt++) acc[nt] = (f32x4){0.f, 0.f, 0.f, 0.f};
#pragma unroll
  for (int ks = 0; ks < 4; ks++) {
    bf16x8 a = *(const bf16x8*)&Tbuf[(rowBase + l16) * TPAD + ks * 32 + quad * 8];
#pragma unroll
    for (int nt = 0; nt < 8; nt++) {
      bf16x8 b = W2v[(nt * 4 + ks) * 64 + lane];
      acc[nt] = __builtin_amdgcn_mfma_f32_16x16x32_bf16(a, b, acc[nt], 0, 0, 0);
    }
  }
#pragma unroll
  for (int nt = 0; nt < 8; nt++) {
    int col = nt * 16 + l16;
    float bb = bm2s[col];
#pragma unroll
    for (int reg = 0; reg < 4; reg++) {
      int row = rowBase + quad * 4 + reg;
      MsgB[row * TPAD + col] = (bf16)silu_f(acc[nt][reg] + bb);
    }
  }

  // ---- coord head: silu(messages @ Wc1 + bc1) @ Wc2 ----
#pragma unroll
  for (int nt = 0; nt < 8; nt++) acc[nt] = (f32x4){0.f, 0.f, 0.f, 0.f};
#pragma unroll
  for (int ks = 0; ks < 4; ks++) {
    bf16x8 a = *(const bf16x8*)&MsgB[(rowBase + l16) * TPAD + ks * 32 + quad * 8];
#pragma unroll
    for (int nt = 0; nt < 8; nt++) {
      bf16x8 b = Wc1v[(nt * 4 + ks) * 64 + lane];
      acc[nt] = __builtin_amdgcn_mfma_f32_16x16x32_bf16(a, b, acc[nt], 0, 0, 0);
    }
  }

  // copy this wave's 16 message rows to global (coalesced 16B chunks)
#pragma unroll
  for (int i = 0; i < 4; i++) {
    int idx = i * 64 + lane;
    int row = rowBase + (idx >> 4), cg = idx & 15;
    *(bf16x8*)&msgOut[(size_t)(blk * 64 + row) * H + cg * 8] =
        *(const bf16x8*)&MsgB[row * TPAD + cg * 8];
  }

  float cwp[4] = {0.f, 0.f, 0.f, 0.f};
#pragma unroll
  for (int nt = 0; nt < 8; nt++) {
    int col = nt * 16 + l16;
    float bb = bc1s[col], w2 = wc2s[col];
#pragma unroll
    for (int reg = 0; reg < 4; reg++)
      cwp[reg] += silu_f(acc[nt][reg] + bb) * w2;
  }
#pragma unroll
  for (int reg = 0; reg < 4; reg++) {
    float s = cwp[reg];
    s += __shfl_xor(s, 1);
    s += __shfl_xor(s, 2);
    s += __shfl_xor(s, 4);
    s += __shfl_xor(s, 8);
    cwp[reg] = s;
  }
  if (l16 == 0) {
#pragma unroll
    for (int reg = 0; reg < 4; reg++) {
      int row = rowBase + quad * 4 + reg;
      size_t Rg = (size_t)blk * 64 + row;
      float inv = 1.0f / (dists[row] + 1e-8f);
      float cw = cwp[reg];
#pragma unroll
      for (int c = 0; c < 3; c++)
        updv[Rg * 3 + c] = cds[row * 3 + c] * inv * cw;
    }
  }
}

// ---------------- x finalize ----------------
// one thread per (atom, batch, comp): signed sum of updv over incident bonds.
__global__ void x_kernel(const float* __restrict__ updv,
                         const int* __restrict__ offsets,
                         const int* __restrict__ degI,
                         const int* __restrict__ adj,
                         const float* __restrict__ x,
                         float* __restrict__ xout) {
  int i = blockIdx.x * 256 + threadIdx.x;
  if (i >= NA * 24) return;
  int a = i / 24, r = i % 24, b = r / 3, c = r % 3;
  int deg = degI[a], off = offsets[a];
  float s = 0.f;
  for (int j = 0; j < deg; j++) {
    int ent = adj[off + j];
    int bond = ent >> 1;
    float sg = (ent & 1) ? 1.0f : -1.0f;   // dst:+, src:-
    s += sg * updv[((size_t)bond * 8 + b) * 3 + c];
  }
  float cnt = deg < 1 ? 1.0f : (float)deg;
  size_t o = ((size_t)b * NA + a) * 3 + c;
  xout[o] = x[o] + s / cnt;
}

// ---------------- node kernel (fused aggregation) ----------------
// Layer-1 K=256 = [h (bf16, register-direct) | agg (gathered register-direct
// from msgB via CSR, fp32 acc -> bf16 frag)]. LDS = Tbuf only, no barriers.
__global__ __launch_bounds__(256, 4) void node_kernel(
    const float* __restrict__ h, const bf16* __restrict__ hb,
    const bf16* __restrict__ msg,
    const int* __restrict__ offsets, const int* __restrict__ degI,
    const int* __restrict__ adj,
    const bf16* __restrict__ Wn1p, const float* __restrict__ bn1,
    const bf16* __restrict__ Wn2p, const float* __restrict__ bn2,
    float* __restrict__ hout) {
  __shared__ __align__(16) bf16 Tbuf[64 * TPAD];

  const int tid = threadIdx.x, blk = blockIdx.x;
  const int lane = tid & 63;
  const int quad = lane >> 4, l16 = lane & 15;
  const int rowBase = (tid >> 6) * 16;

  const int Rg = blk * 64 + rowBase + l16;   // batch*NA + atom
  const int atomA = Rg % NA, batA = Rg / NA;
  const int deg = degI[atomA], off = offsets[atomA];
  const bf16* hrow = hb + (size_t)Rg * H;
  const bf16x8* W1v = (const bf16x8*)Wn1p;
  const bf16x8* W2v = (const bf16x8*)Wn2p;

  f32x4 acc[8];
#pragma unroll
  for (int nt = 0; nt < 8; nt++) acc[nt] = (f32x4){0.f, 0.f, 0.f, 0.f};

  // layer-1 first half: h (bf16) register-direct
#pragma unroll
  for (int ks = 0; ks < 4; ks++) {
    bf16x8 a = *(const bf16x8*)(hrow + ks * 32 + quad * 8);
#pragma unroll
    for (int nt = 0; nt < 8; nt++) {
      bf16x8 b = W1v[(nt * 8 + ks) * 64 + lane];
      acc[nt] = __builtin_amdgcn_mfma_f32_16x16x32_bf16(a, b, acc[nt], 0, 0, 0);
    }
  }
  // layer-1 second half: aggregated — gather from msg rows, fp32 acc in regs
#pragma unroll
  for (int ks2 = 0; ks2 < 4; ks2++) {
    float a8[8] = {0.f, 0.f, 0.f, 0.f, 0.f, 0.f, 0.f, 0.f};
    for (int j = 0; j < deg; j++) {
      int ent = adj[off + j];
      int bond = ent >> 1;
      bf16x8 m = *(const bf16x8*)&msg[((size_t)bond * 8 + batA) * H +
                                      ks2 * 32 + quad * 8];
#pragma unroll
      for (int t = 0; t < 8; t++) a8[t] += (float)m[t];
    }
    bf16x8 af = {(bf16)a8[0], (bf16)a8[1], (bf16)a8[2], (bf16)a8[3],
                 (bf16)a8[4], (bf16)a8[5], (bf16)a8[6], (bf16)a8[7]};
#pragma unroll
    for (int nt = 0; nt < 8; nt++) {
      bf16x8 b = W1v[(nt * 8 + 4 + ks2) * 64 + lane];
      acc[nt] = __builtin_amdgcn_mfma_f32_16x16x32_bf16(af, b, acc[nt], 0, 0, 0);
    }
  }
#pragma unroll
  for (int nt = 0; nt < 8; nt++) {
    int col = nt * 16 + l16;
    float bb = bn1[col];
#pragma unroll
    for (int reg = 0; reg < 4; reg++) {
      int row = rowBase + quad * 4 + reg;
      Tbuf[row * TPAD + col] = (bf16)silu_f(acc[nt][reg] + bb);
    }
  }

#pragma unroll
  for (int nt = 0; nt < 8; nt++) acc[nt] = (f32x4){0.f, 0.f, 0.f, 0.f};
#pragma unroll
  for (int ks = 0; ks < 4; ks++) {
    bf16x8 a = *(const bf16x8*)&Tbuf[(rowBase + l16) * TPAD + ks * 32 + quad * 8];
#pragma unroll
    for (int nt = 0; nt < 8; nt++) {
      bf16x8 b = W2v[(nt * 4 + ks) * 64 + lane];
      acc[nt] = __builtin_amdgcn_mfma_f32_16x16x32_bf16(a, b, acc[nt], 0, 0, 0);
    }
  }
#pragma unroll
  for (int nt = 0; nt < 8; nt++) {
    int col = nt * 16 + l16;
    float bb = bn2[col];
#pragma unroll
    for (int reg = 0; reg < 4; reg++) {
      size_t Ro = (size_t)blk * 64 + rowBase + quad * 4 + reg;
      hout[Ro * H + col] = h[Ro * H + col] + acc[nt][reg] + bb;
    }
  }
}

extern "C" void kernel_launch(void* const* d_in, const int* in_sizes, int n_in,
                              void* d_out, int out_size, void* d_ws,
                              size_t ws_size, hipStream_t stream) {
  const float* h    = (const float*)d_in[0];
  const float* x    = (const float*)d_in[1];
  const int*  bonds = (const int*)d_in[2];
  const float* Wm1  = (const float*)d_in[3];
  const float* bm1  = (const float*)d_in[4];
  const float* Wm2  = (const float*)d_in[5];
  const float* bm2  = (const float*)d_in[6];
  const float* Wn1  = (const float*)d_in[7];
  const float* bn1  = (const float*)d_in[8];
  const float* Wn2  = (const float*)d_in[9];
  const float* bn2  = (const float*)d_in[10];
  const float* Wc1  = (const float*)d_in[11];
  const float* bc1  = (const float*)d_in[12];
  const float* Wc2  = (const float*)d_in[13];

  float* out  = (float*)d_out;
  float* hout = out;
  float* xout = out + (size_t)NBATCH * NA * H;

  char* ws = (char*)d_ws;
  // layout (bytes): NEED = 170,655,744 < 173,080,576 proven available.
  const size_t OFF_DEG  = 0;                        // NA int
  const size_t OFF_OFFS = 81920;                    // NA int
  const size_t OFF_CUR  = 163840;                   // NA int
  const size_t OFF_ADJ  = 245760;                   // 2*NB int = 480,000 B
  const size_t OFF_W1   = 786432;                   // 65,536 B
  const size_t OFF_W2   = OFF_W1 + 65536;           // 32,768
  const size_t OFF_WN1  = OFF_W2 + 32768;           // 65,536
  const size_t OFF_WN2  = OFF_WN1 + 65536;          // 32,768
  const size_t OFF_WC1  = OFF_WN2 + 32768;          // 32,768 (ends 1,015,808)
  const size_t OFF_UPDV = 1048576;                  // NB*8*3 f32 = 5,760,000
  const size_t OFF_HB   = 6815744;                  // 160000*128 bf16 = 40,960,000
  const size_t OFF_MSG  = 47775744;                 // NB*8*128 bf16 = 122,880,000

  int*   degI = (int*)(ws + OFF_DEG);
  int*   offs = (int*)(ws + OFF_OFFS);
  int*   cur  = (int*)(ws + OFF_CUR);
  int*   adj  = (int*)(ws + OFF_ADJ);
  bf16*  W1p  = (bf16*)(ws + OFF_W1);
  bf16*  W2p  = (bf16*)(ws + OFF_W2);
  bf16*  Wn1p = (bf16*)(ws + OFF_WN1);
  bf16*  Wn2p = (bf16*)(ws + OFF_WN2);
  bf16*  Wc1p = (bf16*)(ws + OFF_WC1);
  float* updv = (float*)(ws + OFF_UPDV);
  bf16*  hb   = (bf16*)(ws + OFF_HB);
  bf16*  msgB = (bf16*)(ws + OFF_MSG);

  (void)hipMemsetAsync(degI, 0, NA * sizeof(int), stream);
  (void)hipMemsetAsync(cur, 0, NA * sizeof(int), stream);

  cast_h<<<NBATCH * NA * H / 1024, 256, 0, stream>>>(h, hb);
  pack_w<<<128, 256, 0, stream>>>(Wm1, W1p, 256);
  pack_w<<<64, 256, 0, stream>>>(Wm2, W2p, 128);
  pack_w<<<128, 256, 0, stream>>>(Wn1, Wn1p, 256);
  pack_w<<<64, 256, 0, stream>>>(Wn2, Wn2p, 128);
  pack_w<<<64, 256, 0, stream>>>(Wc1, Wc1p, 128);

  count_deg<<<(NB + 255) / 256, 256, 0, stream>>>(bonds, degI);
  scan_offsets<<<1, 1024, 0, stream>>>(degI, offs);
  build_adj<<<(NB + 255) / 256, 256, 0, stream>>>(bonds, offs, cur, adj);

  msg_kernel<<<NB * NBATCH / 64, 256, 0, stream>>>(
      hb, x, bonds, W1p, bm1, W2p, bm2, Wm1 + 256 * H, Wc1p, bc1, Wc2,
      msgB, updv);
  node_kernel<<<NBATCH * NA / 64, 256, 0, stream>>>(
      h, hb, msgB, offs, degI, adj, Wn1p, bn1, Wn2p, bn2, hout);
  x_kernel<<<(NA * 24 + 255) / 256, 256, 0, stream>>>(updv, offs, degI, adj,
                                                      x, xout);
}